// Round 7
// baseline (230.381 us; speedup 1.0000x reference)
//
#include <hip/hip_runtime.h>
#include <math.h>

#define T_STEPS 96
#define N_NODES 128
#define B_SZ 64
#define H_SZ 64

typedef __attribute__((ext_vector_type(8))) __bf16 bf16x8;
typedef __attribute__((ext_vector_type(4))) float f32x4;

__device__ __forceinline__ float rcp_fast(float x){ return __builtin_amdgcn_rcpf(x); }
__device__ __forceinline__ float exp2_fast(float x){ return __builtin_amdgcn_exp2f(x); }
__device__ __forceinline__ float sigm(float v){ return rcp_fast(1.0f + __expf(-v)); }

// ---------------- LSTM kernel: one fully-independent wave per (node, batch-16) ----
// grid = 512 blocks x 64 threads (task = bq*128 + n for XCD-local w reuse).
// Wave owns all 16 D-tiles (4 gates x 4 h-groups) of gates[256 x 16b]:
//   A = W^T (persistent VGPR bf16, i/f/o pre-scaled by log2e), B = h (bf16, LDS),
//   plus a 3rd k-chunk carrying x(hi/lo) and bias -> no per-step scalar gate init.
// h exchange is intra-wave through wave-private LDS: NO __syncthreads in the loop.
// Cell update lane-local: lane (q,l15) owns batch l15, h = hg*16+q*4+r.
// Combined-rcp gate math: 4 exp2 + 2 rcp per cell (inf-safe, exp(2c) clamped).
__global__ __launch_bounds__(64, 1) void lstm_kernel(
    const float* __restrict__ x, const float* __restrict__ w,
    const float* __restrict__ bias, float* __restrict__ yout)
{
  __shared__ __align__(16) unsigned short hsh[16*72]; // [batch][64 h + 8 pad]
  __shared__ float xsl[T_STEPS*16];                   // [t][16 local batches]

  const int task = blockIdx.x;
  const int bq   = task >> 7;          // 0..3
  const int n    = task & 127;         // node
  const int tid  = threadIdx.x;        // 0..63 (one wave)
  const int l15  = tid & 15;
  const int q    = tid >> 4;

  for (int i = tid; i < 16*72; i += 64) hsh[i] = 0;
  for (int i = tid; i < T_STEPS*16; i += 64){
    int t2 = i >> 4, bl = i & 15;
    xsl[i] = x[(bq*16 + bl)*(T_STEPS*N_NODES) + t2*N_NODES + n];
  }

  const float LOG2E = 1.4426950408889634f;
  const float* wn = w + n*(65*256);

  // A-frags: A[m=l15][k=q*8+j] ; tile tl = g*4+hg covers gate-cols g*64+hg*16..+15
  bf16x8 aF[16][2];
  bf16x8 a2[16];                       // x/bias k-chunk: j0=w0hi j1=bias j2=w0hi j3=w0lo
#pragma unroll
  for (int g = 0; g < 4; ++g){
    const float sc = (g < 3) ? LOG2E : 1.0f;   // i,f,o in log2 domain; c_tilda true
#pragma unroll
    for (int hg = 0; hg < 4; ++hg){
      const int tl  = g*4 + hg;
      const int col = g*64 + hg*16 + l15;
#pragma unroll
      for (int ks = 0; ks < 2; ++ks)
#pragma unroll
        for (int j = 0; j < 8; ++j)
          aF[tl][ks][j] = (__bf16)(wn[(1 + ks*32 + q*8 + j)*256 + col] * sc);
      bf16x8 av;
#pragma unroll
      for (int j = 0; j < 8; ++j) av[j] = (__bf16)0.0f;
      if (q == 0){
        float w0 = wn[col] * sc;
        __bf16 w0h = (__bf16)w0;
        av[0] = w0h;
        av[1] = (__bf16)(bias[n*256 + col] * sc);
        av[2] = w0h;
        av[3] = (__bf16)(w0 - (float)w0h);
      }
      a2[tl] = av;
    }
  }

  f32x4 c4[4], hs4[4];
#pragma unroll
  for (int hg = 0; hg < 4; ++hg){
    c4[hg]  = (f32x4){0.f,0.f,0.f,0.f};
    hs4[hg] = (f32x4){0.f,0.f,0.f,0.f};
  }
  __syncthreads();   // staging visible (one-time; loop itself is barrier-free)

#pragma unroll 1
  for (int t = 0; t < T_STEPS; ++t){
    // B-frags: B[k=q*8+j][n=l15] = h[batch l15][h=k]
    bf16x8 b0 = *(const bf16x8*)&hsh[l15*72 +  0 + q*8];
    bf16x8 b1 = *(const bf16x8*)&hsh[l15*72 + 32 + q*8];
    // x k-chunk: j0=xhi j1=1.0 j2=xlo j3=xhi  (pairs with a2 slots)
    float xv = xsl[t*16 + l15];
    __bf16 xh = (__bf16)xv;
    __bf16 xl = (__bf16)(xv - (float)xh);
    bf16x8 b2;
#pragma unroll
    for (int j = 0; j < 8; ++j) b2[j] = (__bf16)0.0f;
    if (q == 0){ b2[0] = xh; b2[1] = (__bf16)1.0f; b2[2] = xl; b2[3] = xh; }

    f32x4 acc[16];
#pragma unroll
    for (int tl = 0; tl < 16; ++tl){
      f32x4 a = {0.f,0.f,0.f,0.f};
      a = __builtin_amdgcn_mfma_f32_16x16x32_bf16(aF[tl][0], b0, a, 0,0,0);
      a = __builtin_amdgcn_mfma_f32_16x16x32_bf16(aF[tl][1], b1, a, 0,0,0);
      a = __builtin_amdgcn_mfma_f32_16x16x32_bf16(a2[tl],   b2, a, 0,0,0);
      acc[tl] = a;
    }

#pragma unroll
    for (int hg = 0; hg < 4; ++hg){
      f32x4 cv = c4[hg];
      f32x4 hn;
#pragma unroll
      for (int r = 0; r < 4; ++r){
        float gi = acc[0*4+hg][r], gf = acc[1*4+hg][r];
        float go = acc[2*4+hg][r], ct = acc[3*4+hg][r];
        float ei = exp2_fast(-gi), ef = exp2_fast(-gf);
        float pf = 1.0f + ef, pi = 1.0f + ei;
        float num = fmaf(cv[r], ei, cv[r]);          // cv*(1+ei)
        num = fmaf(ct, pf, num);                     // + ct*(1+ef)
        float cn = num * rcp_fast(pf*pi);            // no tanh on c_tilda
        cv[r] = cn;
        float eo = exp2_fast(-go);
        float ea = fminf(cn*2.8853900817779268f, 126.0f);  // 2*log2e, overflow clamp
        float ec = exp2_fast(ea);
        hn[r] = (ec - 1.0f) * rcp_fast((1.0f + eo)*(ec + 1.0f)); // sigm(o)*tanh(c)
      }
      c4[hg]   = cv;
      hs4[hg] += hn;
      ushort4 pk;
      pk.x = __builtin_bit_cast(unsigned short, (__bf16)hn[0]);
      pk.y = __builtin_bit_cast(unsigned short, (__bf16)hn[1]);
      pk.z = __builtin_bit_cast(unsigned short, (__bf16)hn[2]);
      pk.w = __builtin_bit_cast(unsigned short, (__bf16)hn[3]);
      *(ushort4*)&hsh[l15*72 + hg*16 + q*4] = pk;    // intra-wave, lgkmcnt-ordered
    }
  }

#pragma unroll
  for (int hg = 0; hg < 4; ++hg){
    float4 o4 = {hs4[hg][0], hs4[hg][1], hs4[hg][2], hs4[hg][3]};
    *(float4*)&yout[((bq*16 + l15)*N_NODES + n)*H_SZ + hg*16 + q*4] = o4;
  }
}

// ---------------- DFT kernel: m = rfft(y, axis=n, ortho) ----------------
// grid = 256: (b = blockIdx>>2, h-group of 16 = blockIdx&3)
__global__ __launch_bounds__(256, 2) void dft_kernel(
    const float* __restrict__ y, float* __restrict__ Mout)
{
  __shared__ __align__(16) float ysl[128*20];
  __shared__ float twc[128], tws[128];
  const int b   = blockIdx.x >> 2;
  const int hg  = blockIdx.x & 3;
  const int tid = threadIdx.x;

  if (tid < 128){
    float ang = (float)((double)tid * 0.04908738521234052); // 2*pi/128
    twc[tid] = cosf(ang);
    tws[tid] = sinf(ang);
  }
  for (int i = tid; i < 128*16; i += 256){
    int nn = i >> 4, h = i & 15;
    ysl[nn*20 + h] = y[(b*N_NODES + nn)*H_SZ + hg*16 + h];
  }
  __syncthreads();

  for (int o = tid; o < 65*4; o += 256){
    int k  = o >> 2;
    int hq = o & 3;
    float re0=0,re1=0,re2=0,re3=0,im0=0,im1=0,im2=0,im3=0;
    for (int nn = 0; nn < 128; ++nn){
      float4 yv = *(const float4*)&ysl[nn*20 + hq*4];
      int j = (k*nn) & 127;
      float cc = twc[j], ss = tws[j];
      re0 = fmaf(yv.x, cc, re0); im0 = fmaf(yv.x, -ss, im0);
      re1 = fmaf(yv.y, cc, re1); im1 = fmaf(yv.y, -ss, im1);
      re2 = fmaf(yv.z, cc, re2); im2 = fmaf(yv.z, -ss, im2);
      re3 = fmaf(yv.w, cc, re3); im3 = fmaf(yv.w, -ss, im3);
    }
    const float s = 0.08838834764831845f;  // 1/sqrt(128)
    const int hb2 = hg*16 + hq*4;
    float* mre = Mout + ((b*2+0)*65 + k)*H_SZ + hb2;
    float* mim = Mout + ((b*2+1)*65 + k)*H_SZ + hb2;
    mre[0]=re0*s; mre[1]=re1*s; mre[2]=re2*s; mre[3]=re3*s;
    mim[0]=im0*s; mim[1]=im1*s; mim[2]=im2*s; mim[3]=im3*s;
  }
}

// ---------------- epilogue: all-LDS attention algebra + irfft-collapse + LN head ----
// grid = 64 (one block per batch b). Everything staged to LDS up front.
__global__ __launch_bounds__(256, 1) void post_kernel(
    const float* __restrict__ y, const float* __restrict__ Mws,
    const float* __restrict__ ln_g, const float* __restrict__ ln_b,
    const float* __restrict__ fc_w, const float* __restrict__ fc_b,
    float* __restrict__ out)
{
  __shared__ float ysh[128*65];  // [n][h] stride 65
  __shared__ float Mre[65*65];   // [k][h] stride 65
  __shared__ float Mim[65*65];
  __shared__ float twc[128], tws[128];
  __shared__ float Sre[64], Sim[64];
  __shared__ float gr[65], gi[65];
  __shared__ float Gre[64], Gim[64];
  __shared__ float att[128];
  __shared__ float PQ[65*2], AA[65*2];
  __shared__ float outv[64];

  const int b   = blockIdx.x;
  const int tid = threadIdx.x;

  if (tid < 128){
    float ang = (float)((double)tid * 0.04908738521234052);
    twc[tid] = cosf(ang);
    tws[tid] = sinf(ang);
  }
  for (int i = tid; i < 128*16; i += 256){
    int nn = i >> 4, h4 = (i & 15)*4;
    float4 v = *(const float4*)&y[(b*N_NODES + nn)*H_SZ + h4];
    ysh[nn*65 + h4+0] = v.x; ysh[nn*65 + h4+1] = v.y;
    ysh[nn*65 + h4+2] = v.z; ysh[nn*65 + h4+3] = v.w;
  }
  for (int i = tid; i < 65*16; i += 256){
    int k = i >> 4, h4 = (i & 15)*4;
    float4 vr = *(const float4*)&Mws[((b*2+0)*65 + k)*H_SZ + h4];
    float4 vi = *(const float4*)&Mws[((b*2+1)*65 + k)*H_SZ + h4];
    Mre[k*65 + h4+0] = vr.x; Mre[k*65 + h4+1] = vr.y;
    Mre[k*65 + h4+2] = vr.z; Mre[k*65 + h4+3] = vr.w;
    Mim[k*65 + h4+0] = vi.x; Mim[k*65 + h4+1] = vi.y;
    Mim[k*65 + h4+2] = vi.z; Mim[k*65 + h4+3] = vi.w;
  }
  __syncthreads();

  if (tid < 64){
    float sr=0, si=0;
    for (int k = 0; k < 65; ++k){ sr += Mre[k*65+tid]; si += Mim[k*65+tid]; }
    Sre[tid]=sr; Sim[tid]=si;
  }
  __syncthreads();

  if (tid < 65){
    float a=0, bb=0;
    for (int h = 0; h < 64; ++h){
      float mr = Mre[tid*65+h], mi = Mim[tid*65+h];
      a  += mr*Sre[h] - mi*Sim[h];
      bb += mr*Sim[h] + mi*Sre[h];
    }
    a  *= (1.0f/4160.0f);  bb *= (1.0f/4160.0f);
    a = fmaxf(a, 0.0f);    bb = fmaxf(bb, 0.0f);
    float t  = __expf(-a);
    float cb = cosf(bb), sb = sinf(bb);
    float dre = 1.0f + t*cb;
    float dim = t*sb;
    float nrm = rcp_fast(dre*dre + dim*dim);
    gr[tid] = dre*nrm;
    gi[tid] = dim*nrm;
  }
  __syncthreads();

  if (tid < 64){
    float grh=0, gih=0;
    for (int k = 0; k < 65; ++k){
      float mr = Mre[k*65+tid], mi = Mim[k*65+tid];
      float gk = gr[k], hk = gi[k];
      grh += gk*mr - hk*mi;
      gih += gk*mi + hk*mr;
    }
    Gre[tid]=grh; Gim[tid]=gih;
  }
  __syncthreads();

  if (tid < 65){
    float p=0, qq=0;
    for (int h = 0; h < 64; ++h){
      float gimh = Gim[h];
      p  += gimh * Mim[tid*65+h];
      qq += gimh * Mre[tid*65+h];
    }
    const float s2 = 2.0f*0.08838834764831845f;
    PQ[tid*2]   = p*s2;
    PQ[tid*2+1] = qq*s2;
  }
  __syncthreads();

  if (tid < 128){
    float u=0;
    for (int h = 0; h < 64; ++h) u += Gre[h]*ysh[tid*65+h];
    float v=0;
    for (int k = 1; k < 64; ++k){
      int j = (k*tid) & 127;
      v += PQ[k*2]*twc[j] + PQ[k*2+1]*tws[j];
    }
    float mean = (u - v)*(1.0f/64.0f);
    att[tid] = sigm(fmaxf(mean, 0.0f));
  }
  __syncthreads();

  if (tid < 65){
    float ac=0, as=0;
    for (int nn = 0; nn < 128; ++nn){
      int j = (tid*nn) & 127;
      float a2 = att[nn];
      ac = fmaf(a2, twc[j], ac);
      as = fmaf(a2, tws[j], as);
    }
    const float s2 = 2.0f*0.08838834764831845f;
    AA[tid*2]   = ac*s2;
    AA[tid*2+1] = as*s2;
  }
  __syncthreads();

  if (tid < 64){
    float wyh=0;
    for (int nn = 0; nn < 128; ++nn) wyh += att[nn]*ysh[nn*65+tid];
    float wHh=0;
    for (int k = 1; k < 64; ++k)
      wHh += Mim[k*65+tid]*AA[k*2] + Mre[k*65+tid]*AA[k*2+1];
    outv[tid] = Gre[tid]*wyh - Gim[tid]*wHh;
  }
  __syncthreads();

  if (tid < 64){
    float o = outv[tid];
    float s = o;
    for (int off = 32; off; off >>= 1) s += __shfl_xor(s, off, 64);
    float mu = s*(1.0f/64.0f);
    float d  = o - mu;
    float vv = d*d;
    for (int off = 32; off; off >>= 1) vv += __shfl_xor(vv, off, 64);
    float var = vv*(1.0f/64.0f);
    float zo = (d / sqrtf(var + 1e-5f))*ln_g[tid] + ln_b[tid];
    float z  = zo * fc_w[tid];
    for (int off = 32; off; off >>= 1) z += __shfl_xor(z, off, 64);
    if (tid == 0) out[b] = 1.0f/(1.0f + __expf(-(z + fc_b[0])));
  }
}

extern "C" void kernel_launch(void* const* d_in, const int* in_sizes, int n_in,
                              void* d_out, int out_size, void* d_ws, size_t ws_size,
                              hipStream_t stream) {
  (void)in_sizes; (void)n_in; (void)out_size; (void)ws_size;
  const float* x    = (const float*)d_in[0];
  const float* w    = (const float*)d_in[1];
  const float* bia  = (const float*)d_in[2];
  const float* ln_g = (const float*)d_in[3];
  const float* ln_b = (const float*)d_in[4];
  const float* fc_w = (const float*)d_in[5];
  const float* fc_b = (const float*)d_in[6];
  float* out = (float*)d_out;

  float* y = (float*)d_ws;                  // [64][128][64] fp32  (2 MB)
  float* M = y + (size_t)B_SZ*N_NODES*H_SZ; // [64][2][65][64] fp32 (~2.1 MB)

  lstm_kernel<<<dim3(512), dim3(64),  0, stream>>>(x, w, bia, y);
  dft_kernel <<<dim3(256), dim3(256), 0, stream>>>(y, M);
  post_kernel<<<dim3(64),  dim3(256), 0, stream>>>(y, M, ln_g, ln_b, fc_w, fc_b, out);
}

// Round 8
// 172.096 us; speedup vs baseline: 1.3387x; 1.3387x over previous
//
#include <hip/hip_runtime.h>
#include <math.h>

#define T_STEPS 96
#define N_NODES 128
#define B_SZ 64
#define H_SZ 64

typedef __attribute__((ext_vector_type(8))) __bf16 bf16x8;
typedef __attribute__((ext_vector_type(4))) float f32x4;

__device__ __forceinline__ float rcp_fast(float x){ return __builtin_amdgcn_rcpf(x); }
__device__ __forceinline__ float exp2_fast(float x){ return __builtin_amdgcn_exp2f(x); }
__device__ __forceinline__ float sigm(float v){ return rcp_fast(1.0f + __expf(-v)); }

// ---------------- LSTM kernel: 8 waves/block for latency hiding ----------------
// grid = 512 blocks x 512 threads (n = blockIdx>>2, bq = blockIdx&3); 2 blocks/CU
// -> 16 waves/CU = 4 waves/SIMD (R7 post-mortem: TLP per SIMD is the binding
//    resource for this serial-T loop, not barrier count).
// Wave wv owns h-slice [wv*8, wv*8+8) of all 4 gates as TWO 16x16 D-tiles with
// row m = h_local*4 + gate  (col(m) = (m&3)*64 + wv*8 + tile*4 + (m>>2)), so
// lane (q,l15) holds cell (batch=l15, h=wv*8+tile*4+q) with its 4 gates in
// acc[tile][0..3] -> lane-local cell update, 2 cells/lane.
// A = W^T persistent VGPR bf16 (i,f,o pre-scaled by log2e); B = h bf16 in LDS,
// double-buffered, ONE barrier/step. Combined-rcp gates: 4 exp2 + 2 rcp / cell.
__global__ __launch_bounds__(512, 2) void lstm_kernel(
    const float* __restrict__ x, const float* __restrict__ w,
    const float* __restrict__ bias, float* __restrict__ yout)
{
  __shared__ __align__(16) unsigned short hb[2][16*72]; // [buf][batch][64 h + 8 pad]
  __shared__ float xsl[T_STEPS*16];                     // [t][16 local batches]

  const int n   = blockIdx.x >> 2;
  const int bq  = blockIdx.x & 3;
  const int tid = threadIdx.x;
  const int wv  = tid >> 6;            // 0..7
  const int ln  = tid & 63;
  const int l15 = ln & 15;
  const int q   = ln >> 4;

  for (int i = tid; i < 2*16*72; i += 512) ((unsigned short*)hb)[i] = 0;
  for (int i = tid; i < T_STEPS*16; i += 512){
    int t2 = i >> 4, bl = i & 15;
    xsl[i] = x[(bq*16 + bl)*(T_STEPS*N_NODES) + t2*N_NODES + n];
  }

  const float LOG2E = 1.4426950408889634f;
  const float* wn = w + n*(65*256);

  // A-frags: A[m=l15][k=q*8+j (+32)];  col(m,t) = (m&3)*64 + wv*8 + t*4 + (m>>2)
  bf16x8 aF[2][2];
  f32x4 w0t[2], bgt[2];
#pragma unroll
  for (int t = 0; t < 2; ++t){
    const int gA  = l15 & 3;
    const float scA = (gA < 3) ? LOG2E : 1.0f;   // gates [i,f,o] log2-domain, c true
    const int colA = gA*64 + wv*8 + t*4 + (l15 >> 2);
#pragma unroll
    for (int ks = 0; ks < 2; ++ks)
#pragma unroll
      for (int j = 0; j < 8; ++j)
        aF[t][ks][j] = (__bf16)(wn[(1 + ks*32 + q*8 + j)*256 + colA] * scA);
    // D-side rows m=q*4+r -> gate g=r, h=wv*8+t*4+q
#pragma unroll
    for (int r = 0; r < 4; ++r){
      const float sc = (r < 3) ? LOG2E : 1.0f;
      const int colD = r*64 + wv*8 + t*4 + q;
      w0t[t][r] = wn[colD] * sc;
      bgt[t][r] = bias[n*256 + colD] * sc;
    }
  }

  float cv[2]  = {0.f, 0.f};
  float hsv[2] = {0.f, 0.f};
  __syncthreads();

#pragma unroll 2
  for (int t = 0; t < T_STEPS; ++t){
    const unsigned short* cur = hb[t & 1];
    unsigned short*       nxt = (unsigned short*)hb[(t & 1) ^ 1];

    // B-frags: B[k=q*8+j][n=l15] = h[batch l15][h=k]  (all 64 h)
    bf16x8 b0 = *(const bf16x8*)&cur[l15*72 +  0 + q*8];
    bf16x8 b1 = *(const bf16x8*)&cur[l15*72 + 32 + q*8];
    float xv = xsl[t*16 + l15];

    f32x4 acc[2];
#pragma unroll
    for (int tl = 0; tl < 2; ++tl){
      f32x4 a = w0t[tl]*xv + bgt[tl];           // packed x/bias init (fp32 exact)
      a = __builtin_amdgcn_mfma_f32_16x16x32_bf16(aF[tl][0], b0, a, 0,0,0);
      a = __builtin_amdgcn_mfma_f32_16x16x32_bf16(aF[tl][1], b1, a, 0,0,0);
      acc[tl] = a;
    }

#pragma unroll
    for (int tl = 0; tl < 2; ++tl){
      float gi = acc[tl][0], gf = acc[tl][1], go = acc[tl][2], ct = acc[tl][3];
      float ei = exp2_fast(-gi), ef = exp2_fast(-gf);
      float pf = 1.0f + ef, pi = 1.0f + ei;
      float num = fmaf(cv[tl], ei, cv[tl]);      // cv*(1+ei)
      num = fmaf(ct, pf, num);                   // + ct*(1+ef)
      float cn = num * rcp_fast(pf*pi);          // no tanh on c_tilda
      cv[tl] = cn;
      float eo = exp2_fast(-go);
      float ea = fminf(cn*2.8853900817779268f, 126.0f);  // 2*log2e, ovf clamp
      float ec = exp2_fast(ea);
      float hn = (ec - 1.0f) * rcp_fast((1.0f + eo)*(ec + 1.0f)); // sigm(o)*tanh(c)
      hsv[tl] += hn;
      nxt[l15*72 + wv*8 + tl*4 + q] =
          __builtin_bit_cast(unsigned short, (__bf16)hn);
    }
    __syncthreads();   // new h visible to all waves; old buffer reusable
  }

#pragma unroll
  for (int tl = 0; tl < 2; ++tl)
    yout[((bq*16 + l15)*N_NODES + n)*H_SZ + wv*8 + tl*4 + q] = hsv[tl];
}

// ---------------- DFT kernel: m = rfft(y, axis=n, ortho) ----------------
// grid = 256: (b = blockIdx>>2, h-group of 16 = blockIdx&3)
__global__ __launch_bounds__(256, 2) void dft_kernel(
    const float* __restrict__ y, float* __restrict__ Mout)
{
  __shared__ __align__(16) float ysl[128*20];
  __shared__ float twc[128], tws[128];
  const int b   = blockIdx.x >> 2;
  const int hg  = blockIdx.x & 3;
  const int tid = threadIdx.x;

  if (tid < 128){
    float ang = (float)((double)tid * 0.04908738521234052); // 2*pi/128
    twc[tid] = cosf(ang);
    tws[tid] = sinf(ang);
  }
  for (int i = tid; i < 128*16; i += 256){
    int nn = i >> 4, h = i & 15;
    ysl[nn*20 + h] = y[(b*N_NODES + nn)*H_SZ + hg*16 + h];
  }
  __syncthreads();

  for (int o = tid; o < 65*4; o += 256){
    int k  = o >> 2;
    int hq = o & 3;
    float re0=0,re1=0,re2=0,re3=0,im0=0,im1=0,im2=0,im3=0;
    for (int nn = 0; nn < 128; ++nn){
      float4 yv = *(const float4*)&ysl[nn*20 + hq*4];
      int j = (k*nn) & 127;
      float cc = twc[j], ss = tws[j];
      re0 = fmaf(yv.x, cc, re0); im0 = fmaf(yv.x, -ss, im0);
      re1 = fmaf(yv.y, cc, re1); im1 = fmaf(yv.y, -ss, im1);
      re2 = fmaf(yv.z, cc, re2); im2 = fmaf(yv.z, -ss, im2);
      re3 = fmaf(yv.w, cc, re3); im3 = fmaf(yv.w, -ss, im3);
    }
    const float s = 0.08838834764831845f;  // 1/sqrt(128)
    const int hb2 = hg*16 + hq*4;
    float* mre = Mout + ((b*2+0)*65 + k)*H_SZ + hb2;
    float* mim = Mout + ((b*2+1)*65 + k)*H_SZ + hb2;
    mre[0]=re0*s; mre[1]=re1*s; mre[2]=re2*s; mre[3]=re3*s;
    mim[0]=im0*s; mim[1]=im1*s; mim[2]=im2*s; mim[3]=im3*s;
  }
}

// ---------------- epilogue: all-LDS attention algebra + irfft-collapse + LN head ----
// grid = 64 (one block per batch b). Everything staged to LDS up front.
__global__ __launch_bounds__(256, 1) void post_kernel(
    const float* __restrict__ y, const float* __restrict__ Mws,
    const float* __restrict__ ln_g, const float* __restrict__ ln_b,
    const float* __restrict__ fc_w, const float* __restrict__ fc_b,
    float* __restrict__ out)
{
  __shared__ float ysh[128*65];  // [n][h] stride 65
  __shared__ float Mre[65*65];   // [k][h] stride 65
  __shared__ float Mim[65*65];
  __shared__ float twc[128], tws[128];
  __shared__ float Sre[64], Sim[64];
  __shared__ float gr[65], gi[65];
  __shared__ float Gre[64], Gim[64];
  __shared__ float att[128];
  __shared__ float PQ[65*2], AA[65*2];
  __shared__ float outv[64];

  const int b   = blockIdx.x;
  const int tid = threadIdx.x;

  if (tid < 128){
    float ang = (float)((double)tid * 0.04908738521234052);
    twc[tid] = cosf(ang);
    tws[tid] = sinf(ang);
  }
  for (int i = tid; i < 128*16; i += 256){
    int nn = i >> 4, h4 = (i & 15)*4;
    float4 v = *(const float4*)&y[(b*N_NODES + nn)*H_SZ + h4];
    ysh[nn*65 + h4+0] = v.x; ysh[nn*65 + h4+1] = v.y;
    ysh[nn*65 + h4+2] = v.z; ysh[nn*65 + h4+3] = v.w;
  }
  for (int i = tid; i < 65*16; i += 256){
    int k = i >> 4, h4 = (i & 15)*4;
    float4 vr = *(const float4*)&Mws[((b*2+0)*65 + k)*H_SZ + h4];
    float4 vi = *(const float4*)&Mws[((b*2+1)*65 + k)*H_SZ + h4];
    Mre[k*65 + h4+0] = vr.x; Mre[k*65 + h4+1] = vr.y;
    Mre[k*65 + h4+2] = vr.z; Mre[k*65 + h4+3] = vr.w;
    Mim[k*65 + h4+0] = vi.x; Mim[k*65 + h4+1] = vi.y;
    Mim[k*65 + h4+2] = vi.z; Mim[k*65 + h4+3] = vi.w;
  }
  __syncthreads();

  if (tid < 64){
    float sr=0, si=0;
    for (int k = 0; k < 65; ++k){ sr += Mre[k*65+tid]; si += Mim[k*65+tid]; }
    Sre[tid]=sr; Sim[tid]=si;
  }
  __syncthreads();

  if (tid < 65){
    float a=0, bb=0;
    for (int h = 0; h < 64; ++h){
      float mr = Mre[tid*65+h], mi = Mim[tid*65+h];
      a  += mr*Sre[h] - mi*Sim[h];
      bb += mr*Sim[h] + mi*Sre[h];
    }
    a  *= (1.0f/4160.0f);  bb *= (1.0f/4160.0f);
    a = fmaxf(a, 0.0f);    bb = fmaxf(bb, 0.0f);
    float t  = __expf(-a);
    float cb = cosf(bb), sb = sinf(bb);
    float dre = 1.0f + t*cb;
    float dim = t*sb;
    float nrm = rcp_fast(dre*dre + dim*dim);
    gr[tid] = dre*nrm;
    gi[tid] = dim*nrm;
  }
  __syncthreads();

  if (tid < 64){
    float grh=0, gih=0;
    for (int k = 0; k < 65; ++k){
      float mr = Mre[k*65+tid], mi = Mim[k*65+tid];
      float gk = gr[k], hk = gi[k];
      grh += gk*mr - hk*mi;
      gih += gk*mi + hk*mr;
    }
    Gre[tid]=grh; Gim[tid]=gih;
  }
  __syncthreads();

  if (tid < 65){
    float p=0, qq=0;
    for (int h = 0; h < 64; ++h){
      float gimh = Gim[h];
      p  += gimh * Mim[tid*65+h];
      qq += gimh * Mre[tid*65+h];
    }
    const float s2 = 2.0f*0.08838834764831845f;
    PQ[tid*2]   = p*s2;
    PQ[tid*2+1] = qq*s2;
  }
  __syncthreads();

  if (tid < 128){
    float u=0;
    for (int h = 0; h < 64; ++h) u += Gre[h]*ysh[tid*65+h];
    float v=0;
    for (int k = 1; k < 64; ++k){
      int j = (k*tid) & 127;
      v += PQ[k*2]*twc[j] + PQ[k*2+1]*tws[j];
    }
    float mean = (u - v)*(1.0f/64.0f);
    att[tid] = sigm(fmaxf(mean, 0.0f));
  }
  __syncthreads();

  if (tid < 65){
    float ac=0, as=0;
    for (int nn = 0; nn < 128; ++nn){
      int j = (tid*nn) & 127;
      float a2 = att[nn];
      ac = fmaf(a2, twc[j], ac);
      as = fmaf(a2, tws[j], as);
    }
    const float s2 = 2.0f*0.08838834764831845f;
    AA[tid*2]   = ac*s2;
    AA[tid*2+1] = as*s2;
  }
  __syncthreads();

  if (tid < 64){
    float wyh=0;
    for (int nn = 0; nn < 128; ++nn) wyh += att[nn]*ysh[nn*65+tid];
    float wHh=0;
    for (int k = 1; k < 64; ++k)
      wHh += Mim[k*65+tid]*AA[k*2] + Mre[k*65+tid]*AA[k*2+1];
    outv[tid] = Gre[tid]*wyh - Gim[tid]*wHh;
  }
  __syncthreads();

  if (tid < 64){
    float o = outv[tid];
    float s = o;
    for (int off = 32; off; off >>= 1) s += __shfl_xor(s, off, 64);
    float mu = s*(1.0f/64.0f);
    float d  = o - mu;
    float vv = d*d;
    for (int off = 32; off; off >>= 1) vv += __shfl_xor(vv, off, 64);
    float var = vv*(1.0f/64.0f);
    float zo = (d / sqrtf(var + 1e-5f))*ln_g[tid] + ln_b[tid];
    float z  = zo * fc_w[tid];
    for (int off = 32; off; off >>= 1) z += __shfl_xor(z, off, 64);
    if (tid == 0) out[b] = 1.0f/(1.0f + __expf(-(z + fc_b[0])));
  }
}

extern "C" void kernel_launch(void* const* d_in, const int* in_sizes, int n_in,
                              void* d_out, int out_size, void* d_ws, size_t ws_size,
                              hipStream_t stream) {
  (void)in_sizes; (void)n_in; (void)out_size; (void)ws_size;
  const float* x    = (const float*)d_in[0];
  const float* w    = (const float*)d_in[1];
  const float* bia  = (const float*)d_in[2];
  const float* ln_g = (const float*)d_in[3];
  const float* ln_b = (const float*)d_in[4];
  const float* fc_w = (const float*)d_in[5];
  const float* fc_b = (const float*)d_in[6];
  float* out = (float*)d_out;

  float* y = (float*)d_ws;                  // [64][128][64] fp32  (2 MB)
  float* M = y + (size_t)B_SZ*N_NODES*H_SZ; // [64][2][65][64] fp32 (~2.1 MB)

  lstm_kernel<<<dim3(512), dim3(512), 0, stream>>>(x, w, bia, y);
  dft_kernel <<<dim3(256), dim3(256), 0, stream>>>(y, M);
  post_kernel<<<dim3(64),  dim3(256), 0, stream>>>(y, M, ln_g, ln_b, fc_w, fc_b, out);
}

// Round 9
// 168.500 us; speedup vs baseline: 1.3672x; 1.0213x over previous
//
#include <hip/hip_runtime.h>
#include <math.h>

#define T_STEPS 96
#define N_NODES 128
#define B_SZ 64
#define H_SZ 64

typedef __attribute__((ext_vector_type(8))) __bf16 bf16x8;
typedef __attribute__((ext_vector_type(4))) float f32x4;

__device__ __forceinline__ float rcp_fast(float x){ return __builtin_amdgcn_rcpf(x); }
__device__ __forceinline__ float exp2_fast(float x){ return __builtin_amdgcn_exp2f(x); }
__device__ __forceinline__ float sigm(float v){ return rcp_fast(1.0f + __expf(-v)); }

// ---------------- LSTM kernel (R5 structure + log2-domain + combined-rcp) ------
// grid = 512: (node n = blockIdx>>2, batch-quarter bq = blockIdx&3), 4 waves.
// Transposed MFMA: A = W^T persistent VGPR bf16 (i,f,o pre-scaled by log2e),
// B = h bf16 (LDS double-buffered), ONE barrier/step, 8 MFMA/step.
// Lane (q,l15) of wave wv owns batch l15, h = wv*16+q*4+r (lane-local update).
// Cell math: 4 exp2 + 2 rcp (combined-rcp, validated R7/R8, absmax 0.0039).
__global__ __launch_bounds__(256, 2) void lstm_kernel(
    const float* __restrict__ x, const float* __restrict__ w,
    const float* __restrict__ bias, float* __restrict__ yout)
{
  __shared__ __align__(16) unsigned short hb[2][16*72]; // [buf][batch][64 h + 8 pad]
  __shared__ float xsl[T_STEPS*16];                     // [t][16 local batches]

  const int n   = blockIdx.x >> 2;
  const int bq  = blockIdx.x & 3;
  const int tid = threadIdx.x;
  const int wv  = tid >> 6;
  const int ln  = tid & 63;
  const int l15 = ln & 15;
  const int q   = ln >> 4;

  for (int i = tid; i < 2*16*72; i += 256) ((unsigned short*)hb)[i] = 0;
  for (int i = tid; i < T_STEPS*16; i += 256){
    int t2 = i >> 4, bl = i & 15;
    xsl[i] = x[(bq*16 + bl)*(T_STEPS*N_NODES) + t2*N_NODES + n];
  }

  const float LOG2E = 1.4426950408889634f;
  const float* wn = w + n*(65*256);

  // A-frags: A[m=l15][k=q*8+j (+32)] = w[1+k][g*64+wv*16+l15] * scale(g)
  bf16x8 aF[4][2];
  f32x4 w0g[4], bg4[4];
#pragma unroll
  for (int g = 0; g < 4; ++g){
    const float sc = (g < 3) ? LOG2E : 1.0f;   // i,f,o log2-domain; c_tilda true
    const int colA = g*64 + wv*16 + l15;
#pragma unroll
    for (int ks = 0; ks < 2; ++ks)
#pragma unroll
      for (int j = 0; j < 8; ++j)
        aF[g][ks][j] = (__bf16)(wn[(1 + ks*32 + q*8 + j)*256 + colA] * sc);
    // D-side rows m=q*4+r -> h = wv*16+q*4+r ... col for row r:
#pragma unroll
    for (int r = 0; r < 4; ++r){
      const int colD = g*64 + wv*16 + q*4 + r;
      w0g[g][r] = wn[colD] * sc;
      bg4[g][r] = bias[n*256 + colD] * sc;
    }
  }

  f32x4 cv  = {0.f,0.f,0.f,0.f};
  f32x4 hsv = {0.f,0.f,0.f,0.f};
  __syncthreads();

#pragma unroll 2
  for (int t = 0; t < T_STEPS; ++t){
    const unsigned short* cur = hb[t & 1];
    unsigned short*       nxt = (unsigned short*)hb[(t & 1) ^ 1];

    // B-frags: B[k=q*8+j][n=l15] = h[batch l15][h=k]
    bf16x8 b0 = *(const bf16x8*)&cur[l15*72 +  0 + q*8];
    bf16x8 b1 = *(const bf16x8*)&cur[l15*72 + 32 + q*8];
    float xv = xsl[t*16 + l15];

    f32x4 acc[4];
#pragma unroll
    for (int g = 0; g < 4; ++g){
      f32x4 a = w0g[g]*xv + bg4[g];             // packed x/bias init (fp32 exact)
      a = __builtin_amdgcn_mfma_f32_16x16x32_bf16(aF[g][0], b0, a, 0,0,0);
      a = __builtin_amdgcn_mfma_f32_16x16x32_bf16(aF[g][1], b1, a, 0,0,0);
      acc[g] = a;
    }

    f32x4 hn;
#pragma unroll
    for (int r = 0; r < 4; ++r){
      float gi = acc[0][r], gf = acc[1][r], go = acc[2][r], ct = acc[3][r];
      float ei = exp2_fast(-gi), ef = exp2_fast(-gf);
      float pf = 1.0f + ef, pi = 1.0f + ei;
      float num = fmaf(cv[r], ei, cv[r]);        // cv*(1+ei)
      num = fmaf(ct, pf, num);                   // + ct*(1+ef)
      float cn = num * rcp_fast(pf*pi);          // sigm(f)*cv + sigm(i)*ct
      cv[r] = cn;
      float eo = exp2_fast(-go);
      float ea = fminf(cn*2.8853900817779268f, 126.0f);  // 2*log2e, ovf clamp
      float ec = exp2_fast(ea);
      hn[r] = (ec - 1.0f) * rcp_fast((1.0f + eo)*(ec + 1.0f)); // sigm(o)*tanh(c)
    }
    hsv += hn;

    ushort4 pk;
    pk.x = __builtin_bit_cast(unsigned short, (__bf16)hn[0]);
    pk.y = __builtin_bit_cast(unsigned short, (__bf16)hn[1]);
    pk.z = __builtin_bit_cast(unsigned short, (__bf16)hn[2]);
    pk.w = __builtin_bit_cast(unsigned short, (__bf16)hn[3]);
    *(ushort4*)&nxt[l15*72 + wv*16 + q*4] = pk;  // 8B store, 4 consecutive h
    __syncthreads();
  }

  float4 o4 = {hsv[0], hsv[1], hsv[2], hsv[3]};
  *(float4*)&yout[((bq*16 + l15)*N_NODES + n)*H_SZ + wv*16 + q*4] = o4;
}

// ---------------- DFT kernel: m = rfft(y, axis=n, ortho) ----------------
// grid = 256: (b = blockIdx>>2, h-group of 16 = blockIdx&3)
__global__ __launch_bounds__(256, 2) void dft_kernel(
    const float* __restrict__ y, float* __restrict__ Mout)
{
  __shared__ __align__(16) float ysl[128*20];
  __shared__ float twc[128], tws[128];
  const int b   = blockIdx.x >> 2;
  const int hg  = blockIdx.x & 3;
  const int tid = threadIdx.x;

  if (tid < 128){
    float ang = (float)((double)tid * 0.04908738521234052); // 2*pi/128
    twc[tid] = cosf(ang);
    tws[tid] = sinf(ang);
  }
  for (int i = tid; i < 128*16; i += 256){
    int nn = i >> 4, h = i & 15;
    ysl[nn*20 + h] = y[(b*N_NODES + nn)*H_SZ + hg*16 + h];
  }
  __syncthreads();

  for (int o = tid; o < 65*4; o += 256){
    int k  = o >> 2;
    int hq = o & 3;
    float re0=0,re1=0,re2=0,re3=0,im0=0,im1=0,im2=0,im3=0;
    for (int nn = 0; nn < 128; ++nn){
      float4 yv = *(const float4*)&ysl[nn*20 + hq*4];
      int j = (k*nn) & 127;
      float cc = twc[j], ss = tws[j];
      re0 = fmaf(yv.x, cc, re0); im0 = fmaf(yv.x, -ss, im0);
      re1 = fmaf(yv.y, cc, re1); im1 = fmaf(yv.y, -ss, im1);
      re2 = fmaf(yv.z, cc, re2); im2 = fmaf(yv.z, -ss, im2);
      re3 = fmaf(yv.w, cc, re3); im3 = fmaf(yv.w, -ss, im3);
    }
    const float s = 0.08838834764831845f;  // 1/sqrt(128)
    const int hb2 = hg*16 + hq*4;
    float* mre = Mout + ((b*2+0)*65 + k)*H_SZ + hb2;
    float* mim = Mout + ((b*2+1)*65 + k)*H_SZ + hb2;
    mre[0]=re0*s; mre[1]=re1*s; mre[2]=re2*s; mre[3]=re3*s;
    mim[0]=im0*s; mim[1]=im1*s; mim[2]=im2*s; mim[3]=im3*s;
  }
}

// ---------------- epilogue: all-LDS attention algebra + irfft-collapse + LN head ----
// grid = 64 (one block per batch b). Everything staged to LDS up front.
__global__ __launch_bounds__(256, 1) void post_kernel(
    const float* __restrict__ y, const float* __restrict__ Mws,
    const float* __restrict__ ln_g, const float* __restrict__ ln_b,
    const float* __restrict__ fc_w, const float* __restrict__ fc_b,
    float* __restrict__ out)
{
  __shared__ float ysh[128*65];  // [n][h] stride 65
  __shared__ float Mre[65*65];   // [k][h] stride 65
  __shared__ float Mim[65*65];
  __shared__ float twc[128], tws[128];
  __shared__ float Sre[64], Sim[64];
  __shared__ float gr[65], gi[65];
  __shared__ float Gre[64], Gim[64];
  __shared__ float att[128];
  __shared__ float PQ[65*2], AA[65*2];
  __shared__ float outv[64];

  const int b   = blockIdx.x;
  const int tid = threadIdx.x;

  if (tid < 128){
    float ang = (float)((double)tid * 0.04908738521234052);
    twc[tid] = cosf(ang);
    tws[tid] = sinf(ang);
  }
  for (int i = tid; i < 128*16; i += 256){
    int nn = i >> 4, h4 = (i & 15)*4;
    float4 v = *(const float4*)&y[(b*N_NODES + nn)*H_SZ + h4];
    ysh[nn*65 + h4+0] = v.x; ysh[nn*65 + h4+1] = v.y;
    ysh[nn*65 + h4+2] = v.z; ysh[nn*65 + h4+3] = v.w;
  }
  for (int i = tid; i < 65*16; i += 256){
    int k = i >> 4, h4 = (i & 15)*4;
    float4 vr = *(const float4*)&Mws[((b*2+0)*65 + k)*H_SZ + h4];
    float4 vi = *(const float4*)&Mws[((b*2+1)*65 + k)*H_SZ + h4];
    Mre[k*65 + h4+0] = vr.x; Mre[k*65 + h4+1] = vr.y;
    Mre[k*65 + h4+2] = vr.z; Mre[k*65 + h4+3] = vr.w;
    Mim[k*65 + h4+0] = vi.x; Mim[k*65 + h4+1] = vi.y;
    Mim[k*65 + h4+2] = vi.z; Mim[k*65 + h4+3] = vi.w;
  }
  __syncthreads();

  if (tid < 64){
    float sr=0, si=0;
    for (int k = 0; k < 65; ++k){ sr += Mre[k*65+tid]; si += Mim[k*65+tid]; }
    Sre[tid]=sr; Sim[tid]=si;
  }
  __syncthreads();

  if (tid < 65){
    float a=0, bb=0;
    for (int h = 0; h < 64; ++h){
      float mr = Mre[tid*65+h], mi = Mim[tid*65+h];
      a  += mr*Sre[h] - mi*Sim[h];
      bb += mr*Sim[h] + mi*Sre[h];
    }
    a  *= (1.0f/4160.0f);  bb *= (1.0f/4160.0f);
    a = fmaxf(a, 0.0f);    bb = fmaxf(bb, 0.0f);
    float t  = __expf(-a);
    float cb = cosf(bb), sb = sinf(bb);
    float dre = 1.0f + t*cb;
    float dim = t*sb;
    float nrm = rcp_fast(dre*dre + dim*dim);
    gr[tid] = dre*nrm;
    gi[tid] = dim*nrm;
  }
  __syncthreads();

  if (tid < 64){
    float grh=0, gih=0;
    for (int k = 0; k < 65; ++k){
      float mr = Mre[k*65+tid], mi = Mim[k*65+tid];
      float gk = gr[k], hk = gi[k];
      grh += gk*mr - hk*mi;
      gih += gk*mi + hk*mr;
    }
    Gre[tid]=grh; Gim[tid]=gih;
  }
  __syncthreads();

  if (tid < 65){
    float p=0, qq=0;
    for (int h = 0; h < 64; ++h){
      float gimh = Gim[h];
      p  += gimh * Mim[tid*65+h];
      qq += gimh * Mre[tid*65+h];
    }
    const float s2 = 2.0f*0.08838834764831845f;
    PQ[tid*2]   = p*s2;
    PQ[tid*2+1] = qq*s2;
  }
  __syncthreads();

  if (tid < 128){
    float u=0;
    for (int h = 0; h < 64; ++h) u += Gre[h]*ysh[tid*65+h];
    float v=0;
    for (int k = 1; k < 64; ++k){
      int j = (k*tid) & 127;
      v += PQ[k*2]*twc[j] + PQ[k*2+1]*tws[j];
    }
    float mean = (u - v)*(1.0f/64.0f);
    att[tid] = sigm(fmaxf(mean, 0.0f));
  }
  __syncthreads();

  if (tid < 65){
    float ac=0, as=0;
    for (int nn = 0; nn < 128; ++nn){
      int j = (tid*nn) & 127;
      float a2 = att[nn];
      ac = fmaf(a2, twc[j], ac);
      as = fmaf(a2, tws[j], as);
    }
    const float s2 = 2.0f*0.08838834764831845f;
    AA[tid*2]   = ac*s2;
    AA[tid*2+1] = as*s2;
  }
  __syncthreads();

  if (tid < 64){
    float wyh=0;
    for (int nn = 0; nn < 128; ++nn) wyh += att[nn]*ysh[nn*65+tid];
    float wHh=0;
    for (int k = 1; k < 64; ++k)
      wHh += Mim[k*65+tid]*AA[k*2] + Mre[k*65+tid]*AA[k*2+1];
    outv[tid] = Gre[tid]*wyh - Gim[tid]*wHh;
  }
  __syncthreads();

  if (tid < 64){
    float o = outv[tid];
    float s = o;
    for (int off = 32; off; off >>= 1) s += __shfl_xor(s, off, 64);
    float mu = s*(1.0f/64.0f);
    float d  = o - mu;
    float vv = d*d;
    for (int off = 32; off; off >>= 1) vv += __shfl_xor(vv, off, 64);
    float var = vv*(1.0f/64.0f);
    float zo = (d / sqrtf(var + 1e-5f))*ln_g[tid] + ln_b[tid];
    float z  = zo * fc_w[tid];
    for (int off = 32; off; off >>= 1) z += __shfl_xor(z, off, 64);
    if (tid == 0) out[b] = 1.0f/(1.0f + __expf(-(z + fc_b[0])));
  }
}

extern "C" void kernel_launch(void* const* d_in, const int* in_sizes, int n_in,
                              void* d_out, int out_size, void* d_ws, size_t ws_size,
                              hipStream_t stream) {
  (void)in_sizes; (void)n_in; (void)out_size; (void)ws_size;
  const float* x    = (const float*)d_in[0];
  const float* w    = (const float*)d_in[1];
  const float* bia  = (const float*)d_in[2];
  const float* ln_g = (const float*)d_in[3];
  const float* ln_b = (const float*)d_in[4];
  const float* fc_w = (const float*)d_in[5];
  const float* fc_b = (const float*)d_in[6];
  float* out = (float*)d_out;

  float* y = (float*)d_ws;                  // [64][128][64] fp32  (2 MB)
  float* M = y + (size_t)B_SZ*N_NODES*H_SZ; // [64][2][65][64] fp32 (~2.1 MB)

  lstm_kernel<<<dim3(512), dim3(256), 0, stream>>>(x, w, bia, y);
  dft_kernel <<<dim3(256), dim3(256), 0, stream>>>(y, M);
  post_kernel<<<dim3(64),  dim3(256), 0, stream>>>(y, M, ln_g, ln_b, fc_w, fc_b, out);
}